// Round 9
// baseline (220.033 us; speedup 1.0000x reference)
//
#include <hip/hip_runtime.h>
#include <math.h>

#define EPS 1e-5f

typedef unsigned short ushort_t;
typedef __attribute__((ext_vector_type(8))) __bf16 bf16x8;
typedef __attribute__((ext_vector_type(4))) __bf16 bf16x4;
typedef __attribute__((ext_vector_type(4))) float f32x4;

#define MFMA16(a, b, c) __builtin_amdgcn_mfma_f32_16x16x32_bf16(a, b, c, 0, 0, 0)

// 0.125 (attn scale) * log2(e): folded into Q at the QKV epilogue so the
// attention softmax runs directly in base-2 (v_exp_f32 = 2^x).
#define QSCALE2 0.18033688011112042f

__device__ __forceinline__ unsigned short f2bf(float f) {
  unsigned u = __float_as_uint(f);
  u += 0x7fffu + ((u >> 16) & 1u);
  return (unsigned short)(u >> 16);
}

__device__ __forceinline__ void gload16(const void* g, void* l) {
  __builtin_amdgcn_global_load_lds(
      (__attribute__((address_space(1))) void*)(g),
      (__attribute__((address_space(3))) void*)(l), 16, 0, 0);
}

// ---------------- fused cast f32 -> bf16 for all weights + q ----------------
__global__ __launch_bounds__(256) void cast_all_k(
    const float* __restrict__ wq, const float* __restrict__ wk,
    const float* __restrict__ wv, const float* __restrict__ wo,
    const float* __restrict__ w1, const float* __restrict__ w2,
    const float* __restrict__ q, ushort_t* __restrict__ wqkv,
    ushort_t* __restrict__ wob, ushort_t* __restrict__ w1b,
    ushort_t* __restrict__ w2b, ushort_t* __restrict__ qbf) {
  const int b = blockIdx.x;
  const float* src;
  ushort_t* dst;
  int idx;
  if (b < 2048) {
    const int s = b >> 9;
    src = (s == 0) ? wq : (s == 1) ? wk : (s == 2) ? wv : wo;
    dst = (s == 3) ? wob : wqkv + s * 1048576;
    idx = (b & 511) * 2048 + threadIdx.x * 8;
  } else if (b < 4096) {
    src = w1; dst = w1b; idx = (b - 2048) * 2048 + threadIdx.x * 8;
  } else if (b < 6144) {
    src = w2; dst = w2b; idx = (b - 4096) * 2048 + threadIdx.x * 8;
  } else {
    src = q; dst = qbf; idx = (b - 6144) * 2048 + threadIdx.x * 8;
  }
  float4 a = *(const float4*)(src + idx);
  float4 c = *(const float4*)(src + idx + 4);
  uint4 u;
  u.x = (unsigned)f2bf(a.x) | ((unsigned)f2bf(a.y) << 16);
  u.y = (unsigned)f2bf(a.z) | ((unsigned)f2bf(a.w) << 16);
  u.z = (unsigned)f2bf(c.x) | ((unsigned)f2bf(c.y) << 16);
  u.w = (unsigned)f2bf(c.z) | ((unsigned)f2bf(c.w) << 16);
  *(uint4*)(dst + idx) = u;
}

// ---------------- BN eval params (both BNs in one launch) ----------------
__global__ __launch_bounds__(256) void bnparam_k(
    const float* __restrict__ g1, const float* __restrict__ b1,
    const float* __restrict__ m1, const float* __restrict__ v1,
    const float* __restrict__ g2, const float* __restrict__ b2,
    const float* __restrict__ m2, const float* __restrict__ v2,
    float* __restrict__ sc1, float* __restrict__ sh1,
    float* __restrict__ sc2, float* __restrict__ sh2) {
  int i = blockIdx.x * 256 + threadIdx.x;
  if (i < 4096) {
    float s = g1[i] * rsqrtf(v1[i] + EPS);
    sc1[i] = s;
    sh1[i] = b1[i] - m1[i] * s;
  } else if (i < 5120) {
    int j = i - 4096;
    float s = g2[j] * rsqrtf(v2[j] + EPS);
    sc2[j] = s;
    sh2[j] = b2[j] - m2[j] * s;
  }
}

// ---------------- 2-phase GEMM  C[m,n] = sum_k A[m,k]*W[n,k] ----------------
template <int KDIM, int EPI, int TM, int TN, int WM, int WN, int NTHR, int GX, int GY>
__global__ __launch_bounds__(NTHR, 2) void gemm_bt(const ushort_t* __restrict__ A,
                                                   const ushort_t* __restrict__ W,
                                                   const float* __restrict__ p0,
                                                   const float* __restrict__ p1,
                                                   const float* __restrict__ p2,
                                                   float* __restrict__ outF,
                                                   ushort_t* __restrict__ outB) {
  constexpr int BM = 16 * TM * WM, BN = 16 * TN * WN;
  constexpr int LDS_STAGE = 2 * (BM + BN) * 128;  // bytes, 2 bufs
  constexpr int LDS_TR = (EPI == 0) ? 128 * 136 * 2 : 0;
  __shared__ alignas(16) char pool[(LDS_STAGE > LDS_TR) ? LDS_STAGE : LDS_TR];
  constexpr int LA = BM * 8 / NTHR;  // 16B loads per thread for A tile
  constexpr int LB = BN * 8 / NTHR;

  constexpr int NWG = GX * GY;
  const int id = blockIdx.x;
  const int pos = (id & 7) * (NWG / 8) + (id >> 3);
  const int grp = pos / (8 * GX);
  const int rem = pos % (8 * GX);
  const int by = grp * 8 + (rem & 7);
  const int bx = rem >> 3;
  const int bm = by * BM, bn = bx * BN;

  const int tid = threadIdx.x;
  const int lane = tid & 63;
  const int wid = tid >> 6;
  const int wr = wid / WN, wc = wid % WN;
  const int fr = lane & 15;
  const int kg = lane >> 4;

  const char* Ag0 = (const char*)(A + (size_t)bm * KDIM);
  const char* Bg0 = (const char*)(W + (size_t)bn * KDIM);

#define STAGE(bufi, t_)                                                        \
  do {                                                                         \
    const char* Ag = Ag0 + (size_t)(t_)*128;                                   \
    const char* Bg = Bg0 + (size_t)(t_)*128;                                   \
    char* Ab = pool + (bufi) * (BM * 128);                                     \
    char* Bb = pool + 2 * BM * 128 + (bufi) * (BN * 128);                      \
    _Pragma("unroll") for (int li = 0; li < LA; ++li) {                        \
      const int f = li * NTHR + tid;                                           \
      const int row = f >> 3;                                                  \
      const int gl = (f & 7) ^ (row & 7);                                      \
      gload16(Ag + (size_t)row * (KDIM * 2) + gl * 16,                         \
              Ab + (li * NTHR + wid * 64) * 16);                               \
    }                                                                          \
    _Pragma("unroll") for (int li = 0; li < LB; ++li) {                        \
      const int f = li * NTHR + tid;                                           \
      const int row = f >> 3;                                                  \
      const int gl = (f & 7) ^ (row & 7);                                      \
      gload16(Bg + (size_t)row * (KDIM * 2) + gl * 16,                         \
              Bb + (li * NTHR + wid * 64) * 16);                               \
    }                                                                          \
  } while (0)

  f32x4 acc[TM][TN];
#pragma unroll
  for (int i = 0; i < TM; ++i)
#pragma unroll
    for (int j = 0; j < TN; ++j)
#pragma unroll
      for (int r = 0; r < 4; ++r) acc[i][j][r] = 0.f;

  STAGE(0, 0);
  asm volatile("s_waitcnt vmcnt(0)" ::: "memory");
  __builtin_amdgcn_s_barrier();

  constexpr int NT = KDIM / 64;
  for (int t = 0; t < NT; ++t) {
    const int b = t & 1;
    if (t + 1 < NT) STAGE(b ^ 1, t + 1);  // prefetch flies under compute
    const char* Ac = pool + b * (BM * 128);
    const char* Bc = pool + 2 * BM * 128 + b * (BN * 128);
#pragma unroll
    for (int s = 0; s < 2; ++s) {
      bf16x8 bfv[TN];
#pragma unroll
      for (int nf = 0; nf < TN; ++nf) {
        const int row = wc * (16 * TN) + nf * 16 + fr;
        bfv[nf] = *(const bf16x8*)(Bc + row * 128 + (((s * 4 + kg) ^ (row & 7)) * 16));
      }
#pragma unroll
      for (int mf = 0; mf < TM; ++mf) {
        const int row = wr * (16 * TM) + mf * 16 + fr;
        bf16x8 af = *(const bf16x8*)(Ac + row * 128 + (((s * 4 + kg) ^ (row & 7)) * 16));
#pragma unroll
        for (int nf = 0; nf < TN; ++nf) acc[mf][nf] = MFMA16(af, bfv[nf], acc[mf][nf]);
      }
    }
    asm volatile("s_waitcnt vmcnt(0)" ::: "memory");
    __builtin_amdgcn_s_barrier();
  }
#undef STAGE

  if constexpr (EPI == 0) {
    if (bn < 2048) {
#pragma unroll
      for (int mf = 0; mf < TM; ++mf) {
#pragma unroll
        for (int nf = 0; nf < TN; ++nf) {
#pragma unroll
          for (int r = 0; r < 4; ++r) {
            const int m = bm + wr * (16 * TM) + mf * 16 + kg * 4 + r;
            const int n = bn + wc * (16 * TN) + nf * 16 + fr;
            const int sel = n >> 10;
            const int nl = n & 1023;
            float v = acc[mf][nf][r] + ((sel == 0) ? p0[nl] : p1[nl]);
            if (sel == 0) v *= QSCALE2;
            const int b_ = m >> 10, tok = m & 1023;
            const int h_ = nl >> 6, d_ = nl & 63;
            outB[(size_t)sel * 4194304 + (((size_t)(b_ * 16 + h_) * 1024 + tok) * 64 + d_)] =
                f2bf(v);
          }
        }
      }
    } else {
      __syncthreads();
      ushort_t* T = (ushort_t*)pool;  // [128 n][136 m-pad]
#pragma unroll
      for (int mf = 0; mf < TM; ++mf) {
#pragma unroll
        for (int nf = 0; nf < TN; ++nf) {
          const int ml = wr * (16 * TM) + mf * 16 + kg * 4;
          const int nl = wc * (16 * TN) + nf * 16 + fr;
          const float bias = p2[(bn & 1023) + nl];
          bf16x4 pw;
#pragma unroll
          for (int r = 0; r < 4; ++r) pw[r] = (__bf16)(acc[mf][nf][r] + bias);
          *(bf16x4*)(T + nl * 136 + ml) = pw;
        }
      }
      __syncthreads();
      const int b_ = bm >> 10;
      const int tokb = bm & 1023;
#pragma unroll
      for (int it = 0; it < 8; ++it) {
        const int g = it * 256 + tid;
        const int nl = g >> 4;
        const int m0 = (g & 15) * 8;
        bf16x8 v = *(const bf16x8*)(T + nl * 136 + m0);
        const int nloc = (bn - 2048) + nl;
        const int h_ = nloc >> 6, d_ = nloc & 63;
        *(bf16x8*)(outB + 8388608 + (((size_t)(b_ * 16 + h_) * 64 + d_) << 10) + tokb + m0) = v;
      }
    }
  } else {
#pragma unroll
    for (int mf = 0; mf < TM; ++mf) {
#pragma unroll
      for (int nf = 0; nf < TN; ++nf) {
#pragma unroll
        for (int r = 0; r < 4; ++r) {
          const int m = bm + wr * (16 * TM) + mf * 16 + kg * 4 + r;
          const int n = bn + wc * (16 * TN) + nf * 16 + fr;
          float v = acc[mf][nf][r];
          if constexpr (EPI == 1) {
            v += p0[n] + p1[(size_t)m * 1024 + n];
            outF[(size_t)m * 1024 + n] = v;
          } else {
            outF[(size_t)m * 1024 + n] = v * p0[n] + p1[n];
          }
        }
      }
    }
  }
}

// ------- fine-interleaved 3-buffer GEMM (MLP1: BN+GELU->bf16), T3+T4 --------
// BM=256, BN=128, BK=64, 512 thr / 8 waves (2M x 4N), wave tile 128x32.
// 3 full rotating LDS buffers (147 KB): buf[t%3] holds tile t; stage of tile
// t+2 -> buf[(t+2)%3] is ALWAYS disjoint from the two live tiles, so stages
// are sprinkled one chunk per phase (fine interleave). 4 phases per K-tile:
// {ds-read subtile ; stage chunk ; barrier ; lgkmcnt(0) ; 8 MFMA ; barrier}.
// vmcnt(6) at P4 = this iteration's own 6 stage-loads stay in flight; all
// older (tile t+1, staged a full iteration ago) are forced complete.
template <int KDIM, int GX, int GY>
__global__ __launch_bounds__(512, 1) void gemm_fi(const ushort_t* __restrict__ A,
                                                  const ushort_t* __restrict__ W,
                                                  const float* __restrict__ sc,
                                                  const float* __restrict__ sh,
                                                  ushort_t* __restrict__ outB) {
  __shared__ alignas(16) char pool[3 * 49152];  // buf j: A @ j*49152 (32KB), B @ +32768 (16KB)

  constexpr int NWG = GX * GY;
  const int id = blockIdx.x;
  const int pos = (id & 7) * (NWG / 8) + (id >> 3);
  const int grp = pos / (8 * GX);
  const int rem = pos % (8 * GX);
  const int by = grp * 8 + (rem & 7);
  const int bx = rem >> 3;
  const int bm = by * 256, bn = bx * 128;

  const int tid = threadIdx.x;
  const int lane = tid & 63;
  const int wid = tid >> 6;
  const int wr = wid >> 2;  // 0..1  (M half: 128 rows)
  const int wc = wid & 3;   // 0..3  (N quarter: 32 cols)
  const int fr = lane & 15;
  const int kg = lane >> 4;

  const char* Ag0 = (const char*)(A + (size_t)bm * KDIM);
  const char* Bg0 = (const char*)(W + (size_t)bn * KDIM);

  // A tile = 4 load-steps (li 0..3, 64 rows each); B tile = 2 (li 0..1).
#define FI_A(j, t_, li)                                                        \
  do {                                                                         \
    const int f = (li)*512 + tid;                                              \
    const int row = f >> 3;                                                    \
    const int gl = (f & 7) ^ (row & 7);                                        \
    gload16(Ag0 + (size_t)row * (KDIM * 2) + (size_t)(t_)*128 + gl * 16,       \
            pool + (j)*49152 + ((li)*512 + wid * 64) * 16);                    \
  } while (0)
#define FI_B(j, t_, li)                                                        \
  do {                                                                         \
    const int f = (li)*512 + tid;                                              \
    const int row = f >> 3;                                                    \
    const int gl = (f & 7) ^ (row & 7);                                        \
    gload16(Bg0 + (size_t)row * (KDIM * 2) + (size_t)(t_)*128 + gl * 16,       \
            pool + (j)*49152 + 32768 + ((li)*512 + wid * 64) * 16);            \
  } while (0)
#define FI_LDA(mh, s)                                                          \
  _Pragma("unroll") for (int mf2 = 0; mf2 < 4; ++mf2) {                        \
    const int row = wr * 128 + (mh)*64 + mf2 * 16 + fr;                        \
    af[mf2] = *(const bf16x8*)(Ac + row * 128 + ((((s)*4 + kg) ^ (row & 7)) * 16)); \
  }
#define FI_LDB(s)                                                              \
  _Pragma("unroll") for (int nf = 0; nf < 2; ++nf) {                           \
    const int row = wc * 32 + nf * 16 + fr;                                    \
    bfv[nf] = *(const bf16x8*)(Bc + row * 128 + ((((s)*4 + kg) ^ (row & 7)) * 16)); \
  }
#define FI_MFMA(mh)                                                            \
  __builtin_amdgcn_s_setprio(1);                                               \
  _Pragma("unroll") for (int mf2 = 0; mf2 < 4; ++mf2)                          \
  _Pragma("unroll") for (int nf = 0; nf < 2; ++nf)                             \
      acc[(mh)*4 + mf2][nf] = MFMA16(af[mf2], bfv[nf], acc[(mh)*4 + mf2][nf]); \
  __builtin_amdgcn_s_setprio(0);
#define FI_BAR __builtin_amdgcn_s_barrier()
#define FI_LGK asm volatile("s_waitcnt lgkmcnt(0)" ::: "memory")

  f32x4 acc[8][2];
#pragma unroll
  for (int i = 0; i < 8; ++i)
#pragma unroll
    for (int j = 0; j < 2; ++j)
#pragma unroll
      for (int r = 0; r < 4; ++r) acc[i][j][r] = 0.f;

  // prologue: tiles 0 and 1 fully staged (12 loads/thread)
  FI_A(0, 0, 0); FI_A(0, 0, 1); FI_A(0, 0, 2); FI_A(0, 0, 3);
  FI_B(0, 0, 0); FI_B(0, 0, 1);
  FI_A(1, 1, 0); FI_A(1, 1, 1); FI_A(1, 1, 2); FI_A(1, 1, 3);
  FI_B(1, 1, 0); FI_B(1, 1, 1);
  asm volatile("s_waitcnt vmcnt(6)" ::: "memory");  // tile0 resident
  __builtin_amdgcn_s_barrier();

  constexpr int NT = KDIM / 64;
  int j = 0, jn = 2;
  for (int t = 0; t < NT; ++t) {
    const char* Ac = pool + j * 49152;
    const char* Bc = pool + j * 49152 + 32768;
    const bool more = (t + 2 < NT);
    bf16x8 af[4], bfv[2];
    // P1: (mh0, s0)
    FI_LDA(0, 0); FI_LDB(0);
    if (more) { FI_A(jn, t + 2, 0); FI_A(jn, t + 2, 1); }
    FI_BAR; FI_LGK; FI_MFMA(0); FI_BAR;
    // P2: (mh1, s0)
    FI_LDA(1, 0);
    if (more) { FI_A(jn, t + 2, 2); FI_A(jn, t + 2, 3); }
    FI_BAR; FI_LGK; FI_MFMA(1); FI_BAR;
    // P3: (mh0, s1)
    FI_LDA(0, 1); FI_LDB(1);
    if (more) { FI_B(jn, t + 2, 0); }
    FI_BAR; FI_LGK; FI_MFMA(0); FI_BAR;
    // P4: (mh1, s1) + counted wait
    FI_LDA(1, 1);
    if (more) {
      FI_B(jn, t + 2, 1);
      asm volatile("s_waitcnt vmcnt(6)" ::: "memory");  // tile t+1 forced done
    } else {
      asm volatile("s_waitcnt vmcnt(0)" ::: "memory");  // tail drain
    }
    FI_BAR; FI_LGK; FI_MFMA(1); FI_BAR;
    j = (j + 1 == 3) ? 0 : j + 1;
    jn = (jn + 1 == 3) ? 0 : jn + 1;
  }
#undef FI_A
#undef FI_B
#undef FI_LDA
#undef FI_LDB
#undef FI_MFMA
#undef FI_BAR
#undef FI_LGK

  // epilogue: BN + tanh-GELU -> bf16
#pragma unroll
  for (int mf = 0; mf < 8; ++mf) {
#pragma unroll
    for (int nf = 0; nf < 2; ++nf) {
      const int n = bn + wc * 32 + nf * 16 + fr;
      const float scn = sc[n], shn = sh[n];
#pragma unroll
      for (int r = 0; r < 4; ++r) {
        const int m = bm + wr * 128 + mf * 16 + kg * 4 + r;
        float tt = acc[mf][nf][r] * scn + shn;
        float u = tt * (0.7978845608f + 0.0356774081f * tt * tt);
        float e = exp2f(u * 2.8853900818f);
        float ge = tt * (1.f - 1.f / (e + 1.f));
        outB[(size_t)m * 4096 + n] = f2bf(ge);
      }
    }
  }
}

// ---------------- 3-stage counted-vmcnt GEMM (MLP2: BN -> f32) ----------------
template <int KDIM, int TM, int TN, int GX, int GY>
__global__ __launch_bounds__(256, 2) void gemm3s(const ushort_t* __restrict__ A,
                                                 const ushort_t* __restrict__ W,
                                                 const float* __restrict__ sc,
                                                 const float* __restrict__ sh,
                                                 float* __restrict__ outF) {
  constexpr int BM = 32 * TM, BN = 32 * TN;
  __shared__ alignas(16) char pool[3 * (BM + BN) * 128];
  constexpr int LA = BM * 8 / 256;
  constexpr int LB = BN * 8 / 256;

  constexpr int NWG = GX * GY;
  const int id = blockIdx.x;
  const int pos = (id & 7) * (NWG / 8) + (id >> 3);
  const int grp = pos / (8 * GX);
  const int rem = pos % (8 * GX);
  const int by = grp * 8 + (rem & 7);
  const int bx = rem >> 3;
  const int bm = by * BM, bn = bx * BN;

  const int tid = threadIdx.x;
  const int lane = tid & 63;
  const int wid = tid >> 6;
  const int wr = wid >> 1, wc = wid & 1;
  const int fr = lane & 15;
  const int kg = lane >> 4;

  const char* Ag0 = (const char*)(A + (size_t)bm * KDIM);
  const char* Bg0 = (const char*)(W + (size_t)bn * KDIM);

#define STAGE3(bufi, t_)                                                       \
  do {                                                                         \
    const char* Ag = Ag0 + (size_t)(t_)*128;                                   \
    const char* Bg = Bg0 + (size_t)(t_)*128;                                   \
    char* Ab = pool + (bufi) * (BM * 128);                                     \
    char* Bb = pool + 3 * BM * 128 + (bufi) * (BN * 128);                      \
    _Pragma("unroll") for (int li = 0; li < LA; ++li) {                        \
      const int f = li * 256 + tid;                                            \
      const int row = f >> 3;                                                  \
      const int gl = (f & 7) ^ (row & 7);                                      \
      gload16(Ag + (size_t)row * (KDIM * 2) + gl * 16,                         \
              Ab + (li * 256 + wid * 64) * 16);                                \
    }                                                                          \
    _Pragma("unroll") for (int li = 0; li < LB; ++li) {                        \
      const int f = li * 256 + tid;                                            \
      const int row = f >> 3;                                                  \
      const int gl = (f & 7) ^ (row & 7);                                      \
      gload16(Bg + (size_t)row * (KDIM * 2) + gl * 16,                         \
              Bb + (li * 256 + wid * 64) * 16);                                \
    }                                                                          \
  } while (0)

  f32x4 acc[TM][TN];
#pragma unroll
  for (int i = 0; i < TM; ++i)
#pragma unroll
    for (int j = 0; j < TN; ++j)
#pragma unroll
      for (int r = 0; r < 4; ++r) acc[i][j][r] = 0.f;

  STAGE3(0, 0);
  STAGE3(1, 1);
  asm volatile("s_waitcnt vmcnt(6)" ::: "memory");
  __builtin_amdgcn_s_barrier();

  constexpr int NT = KDIM / 64;
  int cb = 0;
  for (int t = 0; t < NT; ++t) {
    if (t + 2 < NT) {
      const int nb = (cb + 2 >= 3) ? cb - 1 : cb + 2;
      STAGE3(nb, t + 2);
    }
    const char* Ac = pool + cb * (BM * 128);
    const char* Bc = pool + 3 * BM * 128 + cb * (BN * 128);
#pragma unroll
    for (int s = 0; s < 2; ++s) {
      bf16x8 bfv[TN];
#pragma unroll
      for (int nf = 0; nf < TN; ++nf) {
        const int row = wc * (16 * TN) + nf * 16 + fr;
        bfv[nf] = *(const bf16x8*)(Bc + row * 128 + (((s * 4 + kg) ^ (row & 7)) * 16));
      }
#pragma unroll
      for (int mf = 0; mf < TM; ++mf) {
        const int row = wr * (16 * TM) + mf * 16 + fr;
        bf16x8 af = *(const bf16x8*)(Ac + row * 128 + (((s * 4 + kg) ^ (row & 7)) * 16));
#pragma unroll
        for (int nf = 0; nf < TN; ++nf) acc[mf][nf] = MFMA16(af, bfv[nf], acc[mf][nf]);
      }
    }
    if (t + 2 < NT)
      asm volatile("s_waitcnt vmcnt(6)" ::: "memory");
    else
      asm volatile("s_waitcnt vmcnt(0)" ::: "memory");
    asm volatile("s_waitcnt lgkmcnt(0)" ::: "memory");
    __builtin_amdgcn_s_barrier();
    cb = (cb + 1 >= 3) ? 0 : cb + 1;
  }
#undef STAGE3

#pragma unroll
  for (int mf = 0; mf < TM; ++mf) {
#pragma unroll
    for (int nf = 0; nf < TN; ++nf) {
      const int n = bn + wc * (16 * TN) + nf * 16 + fr;
      const float scn = sc[n], shn = sh[n];
#pragma unroll
      for (int r = 0; r < 4; ++r) {
        const int m = bm + wr * (16 * TM) + mf * 16 + kg * 4 + r;
        outF[(size_t)m * 1024 + n] = acc[mf][nf][r] * scn + shn;
      }
    }
  }
}

// ---------------- flash attention (swapped QK^T, LDS-staged K/V, dbuf) -------
// + defer-max (T13): skip O-rescale when per-tile max growth <= 8*log2e.
__global__ __launch_bounds__(512) void attn_k(const ushort_t* __restrict__ qp,
                                              const ushort_t* __restrict__ kp,
                                              const ushort_t* __restrict__ vt,
                                              ushort_t* __restrict__ aout) {
  __shared__ ushort_t Kt[2][4096];
  __shared__ ushort_t Vt[2][4096];
  __shared__ ushort_t P[8][16][72];
  const int tid = threadIdx.x;
  const int lane = tid & 63;
  const int wid = tid >> 6;
  const int fr = lane & 15;
  const int kg = lane >> 4;
  const int id = blockIdx.x;
  const int slot = id >> 3;
  const int bh = ((id & 7) << 3) | (slot >> 3);  // 8 heads per XCD chunk
  const int qc = slot & 7;
  const int b_ = bh >> 4, h_ = bh & 15;

  const size_t base = (size_t)bh << 10;
  const int qrow = qc * 128 + wid * 16 + fr;
  bf16x8 qf0 = *(const bf16x8*)(qp + ((base + qrow) << 6) + kg * 8);
  bf16x8 qf1 = *(const bf16x8*)(qp + ((base + qrow) << 6) + 32 + kg * 8);

  const int srow = tid >> 3;
  const int sg16 = ((tid & 7) ^ (srow & 7)) * 16;
  const char* kTileB = (const char*)kp + ((size_t)bh << 17);
  const char* vTileB = (const char*)vt + ((size_t)bh << 17);
  const size_t koff = (size_t)srow * 128 + sg16;   // + kt*8192
  const size_t voff = (size_t)srow * 2048 + sg16;  // + kt*128

#define STAGE(bufi, kt_)                                                      \
  do {                                                                        \
    gload16(kTileB + (size_t)(kt_)*8192 + koff, (char*)Kt[bufi] + wid * 1024); \
    gload16(vTileB + (size_t)(kt_)*128 + voff, (char*)Vt[bufi] + wid * 1024);  \
  } while (0)

  f32x4 oacc[4];
#pragma unroll
  for (int d = 0; d < 4; ++d)
#pragma unroll
    for (int r = 0; r < 4; ++r) oacc[d][r] = 0.f;
  float mrun = -3.0e38f, lrun = 0.f;

  STAGE(0, 0);
  __syncthreads();

  for (int kt = 0; kt < 16; ++kt) {
    const int c = kt & 1;
    if (kt < 15) STAGE(c ^ 1, kt + 1);
    const char* Kc = (const char*)Kt[c];
    const char* Vc = (const char*)Vt[c];

    f32x4 sacc[4];
#pragma unroll
    for (int nf = 0; nf < 4; ++nf)
#pragma unroll
      for (int r = 0; r < 4; ++r) sacc[nf][r] = 0.f;
    __builtin_amdgcn_s_setprio(1);
#pragma unroll
    for (int nf = 0; nf < 4; ++nf) {
      const int r_ = nf * 16 + fr;
      const char* kr = Kc + r_ * 128;
      bf16x8 kf0 = *(const bf16x8*)(kr + ((kg ^ (r_ & 7)) * 16));
      bf16x8 kf1 = *(const bf16x8*)(kr + (((kg + 4) ^ (r_ & 7)) * 16));
      sacc[nf] = MFMA16(kf0, qf0, sacc[nf]);
      sacc[nf] = MFMA16(kf1, qf1, sacc[nf]);
    }
    __builtin_amdgcn_s_setprio(0);
    float mx = sacc[0][0];
#pragma unroll
    for (int nf = 0; nf < 4; ++nf)
#pragma unroll
      for (int r = 0; r < 4; ++r) mx = fmaxf(mx, sacc[nf][r]);
    mx = fmaxf(mx, __shfl_xor(mx, 16));
    mx = fmaxf(mx, __shfl_xor(mx, 32));
    // defer-max: if the tile max grew by <= 8*log2e (base-2 logits), keep the
    // old running max -- P bounded by 2^11.54, f32/bf16 headroom is ample.
    const bool skip = __all((mx - mrun) <= 11.5416f);
    const float mn = skip ? mrun : fmaxf(mrun, mx);
    float rs = 0.f;
#pragma unroll
    for (int nf = 0; nf < 4; ++nf) {
      bf16x4 pw;
#pragma unroll
      for (int r = 0; r < 4; ++r) {
        float ev = exp2f(sacc[nf][r] - mn);
        rs += ev;
        pw[r] = (__bf16)ev;
      }
      *(bf16x4*)(&P[wid][fr][nf * 16 + kg * 4]) = pw;
    }
    rs += __shfl_xor(rs, 16);
    rs += __shfl_xor(rs, 32);
    if (skip) {
      lrun += rs;
    } else {
      const float c_ = exp2f(mrun - mn);
      lrun = lrun * c_ + rs;
      mrun = mn;
      float cb[4];
#pragma unroll
      for (int r = 0; r < 4; ++r) cb[r] = __shfl(c_, kg * 4 + r);
#pragma unroll
      for (int d = 0; d < 4; ++d)
#pragma unroll
        for (int r = 0; r < 4; ++r) oacc[d][r] *= cb[r];
    }
    bf16x8 pa0 = *(const bf16x8*)(&P[wid][fr][kg * 8]);
    bf16x8 pa1 = *(const bf16x8*)(&P[wid][fr][32 + kg * 8]);
    __builtin_amdgcn_s_setprio(1);
#pragma unroll
    for (int df = 0; df < 4; ++df) {
      const int r_ = df * 16 + fr;
      const char* vr_ = Vc + r_ * 128;
      bf16x8 vf0 = *(const bf16x8*)(vr_ + ((kg ^ (r_ & 7)) * 16));
      bf16x8 vf1 = *(const bf16x8*)(vr_ + (((kg + 4) ^ (r_ & 7)) * 16));
      oacc[df] = MFMA16(pa0, vf0, oacc[df]);
      oacc[df] = MFMA16(pa1, vf1, oacc[df]);
    }
    __builtin_amdgcn_s_setprio(0);
    __syncthreads();
  }
#undef STAGE

  float linv[4];
#pragma unroll
  for (int r = 0; r < 4; ++r) linv[r] = 1.f / __shfl(lrun, kg * 4 + r);
#pragma unroll
  for (int df = 0; df < 4; ++df) {
#pragma unroll
    for (int r = 0; r < 4; ++r) {
      const int tok = qc * 128 + wid * 16 + kg * 4 + r;
      const int d_ = df * 16 + fr;
      aout[((size_t)(b_ * 1024 + tok) * 16 + h_) * 64 + d_] = f2bf(oacc[df][r] * linv[r]);
    }
  }
}

// ---------------- LayerNorm over rows of 1024 ----------------
template <int MODE>
__global__ __launch_bounds__(256) void ln_k(const float* __restrict__ in1,
                                            const float* __restrict__ in2,
                                            const float* __restrict__ g,
                                            const float* __restrict__ bt,
                                            float* __restrict__ outF,
                                            ushort_t* __restrict__ outB) {
  const int row = blockIdx.x;
  const int tid = threadIdx.x;
  const size_t off = (size_t)row * 1024 + tid * 4;
  float4 v = *(const float4*)(in1 + off);
  if (MODE == 1) {
    float4 u = *(const float4*)(in2 + off);
    v.x += u.x; v.y += u.y; v.z += u.z; v.w += u.w;
  }
  float s = v.x + v.y + v.z + v.w;
  float q = v.x * v.x + v.y * v.y + v.z * v.z + v.w * v.w;
#pragma unroll
  for (int o = 32; o > 0; o >>= 1) {
    s += __shfl_down(s, o);
    q += __shfl_down(q, o);
  }
  __shared__ float rs[4], rq[4], stat[2];
  const int wid = tid >> 6, lane = tid & 63;
  if (lane == 0) { rs[wid] = s; rq[wid] = q; }
  __syncthreads();
  if (tid == 0) {
    float S = rs[0] + rs[1] + rs[2] + rs[3];
    float Q = rq[0] + rq[1] + rq[2] + rq[3];
    float mean = S * (1.f / 1024.f);
    float var = Q * (1.f / 1024.f) - mean * mean;
    stat[0] = mean;
    stat[1] = rsqrtf(var + EPS);
  }
  __syncthreads();
  const float mean = stat[0], rstd = stat[1];
  const int c = tid * 4;
  float4 o4;
  o4.x = (v.x - mean) * rstd * g[c] + bt[c];
  o4.y = (v.y - mean) * rstd * g[c + 1] + bt[c + 1];
  o4.z = (v.z - mean) * rstd * g[c + 2] + bt[c + 2];
  o4.w = (v.w - mean) * rstd * g[c + 3] + bt[c + 3];
  *(float4*)(outF + off) = o4;
  if (MODE == 0) {
    ushort4 ub;
    ub.x = f2bf(o4.x); ub.y = f2bf(o4.y); ub.z = f2bf(o4.z); ub.w = f2bf(o4.w);
    *(ushort4*)(outB + off) = ub;
  }
}

extern "C" void kernel_launch(void* const* d_in, const int* in_sizes, int n_in,
                              void* d_out, int out_size, void* d_ws, size_t ws_size,
                              hipStream_t stream) {
  const float* q    = (const float*)d_in[0];
  const float* wq   = (const float*)d_in[1];
  const float* bq   = (const float*)d_in[2];
  const float* wk   = (const float*)d_in[3];
  const float* bk   = (const float*)d_in[4];
  const float* wv   = (const float*)d_in[5];
  const float* bv   = (const float*)d_in[6];
  const float* wo   = (const float*)d_in[7];
  const float* bo   = (const float*)d_in[8];
  const float* w1   = (const float*)d_in[9];
  const float* bn1g = (const float*)d_in[10];
  const float* bn1b = (const float*)d_in[11];
  const float* bn1m = (const float*)d_in[12];
  const float* bn1v = (const float*)d_in[13];
  const float* w2   = (const float*)d_in[14];
  const float* bn2g = (const float*)d_in[15];
  const float* bn2b = (const float*)d_in[16];
  const float* bn2m = (const float*)d_in[17];
  const float* bn2v = (const float*)d_in[18];
  const float* ln1g = (const float*)d_in[19];
  const float* ln1b = (const float*)d_in[20];
  const float* ln3g = (const float*)d_in[21];
  const float* ln3b = (const float*)d_in[22];

  char* ws = (char*)d_ws;
  const size_t MB = 1u << 20;
  ushort_t* wqkv = (ushort_t*)(ws);            // 6 MB  [3072,1024]
  ushort_t* w1b  = (ushort_t*)(ws + 6 * MB);   // 8 MB  [4096,1024]
  ushort_t* w2b  = (ushort_t*)(ws + 14 * MB);  // 8 MB  [1024,4096]
  ushort_t* wob  = (ushort_t*)(ws + 22 * MB);  // 2 MB  [1024,1024]
  float* sc1 = (float*)(ws + 24 * MB);
  float* sh1 = sc1 + 4096;
  float* sc2 = sh1 + 4096;
  float* sh2 = sc2 + 1024;
  ushort_t* qbf  = (ushort_t*)(ws + 25 * MB);  // 8 MB
  ushort_t* qp   = (ushort_t*)(ws + 33 * MB);  // 8+8+8 MB (qp,kp,vt contiguous)
  ushort_t* aout = (ushort_t*)(ws + 57 * MB);  // 8 MB
  ushort_t* xbf  = (ushort_t*)(ws + 65 * MB);  // 8 MB
  float*    h2   = (float*)(ws + 73 * MB);     // 16 MB
  ushort_t* h1   = (ushort_t*)(ws + 33 * MB);  // 32 MB (reuses qp/kp/vt/aout)
  float* X = (float*)d_out;                    // x lives in d_out (16 MB)

  const int NM = 1024 * 1024;
  cast_all_k<<<8192, 256, 0, stream>>>(wq, wk, wv, wo, w1, w2, q, wqkv, wob, w1b, w2b, qbf);
  bnparam_k<<<20, 256, 0, stream>>>(bn1g, bn1b, bn1m, bn1v, bn2g, bn2b, bn2m, bn2v,
                                    sc1, sh1, sc2, sh2);

  // fused QKV projection: [4096,1024] x [3072,1024]^T, 128x128 dbuf
  gemm_bt<1024, 0, 4, 4, 2, 2, 256, 24, 32><<<768, 256, 0, stream>>>(
      qbf, wqkv, bq, bk, bv, nullptr, qp);
  // attention (512 blocks x 512 threads, LDS-staged K/V double-buffered)
  attn_k<<<512, 512, 0, stream>>>(qp, qp + 4 * NM, qp + 8 * NM, aout);
  // O projection + bias + residual -> X (f32, in d_out), 128x64 dbuf
  gemm_bt<1024, 1, 4, 2, 2, 2, 256, 16, 32><<<512, 256, 0, stream>>>(
      aout, wob, bo, q, nullptr, X, nullptr);
  // LN1 -> X (in place) + xbf
  ln_k<0><<<4096, 256, 0, stream>>>(X, nullptr, ln1g, ln1b, X, xbf);
  // MLP1: [4096,1024] x [4096,1024]^T -> BN+GELU(tanh) -> h1 bf16,
  // 256x128 fine-interleaved 3-buffer (T3+T4)
  gemm_fi<1024, 32, 16><<<512, 512, 0, stream>>>(xbf, w1b, sc1, sh1, h1);
  // MLP2: [4096,4096] x [1024,4096]^T -> BN -> h2 f32, 128x64 3-stage
  gemm3s<4096, 4, 2, 16, 32><<<512, 256, 0, stream>>>(h1, w2b, sc2, sh2, h2);
  // LN3(X + h2) -> d_out
  ln_k<1><<<4096, 256, 0, stream>>>(X, h2, ln3g, ln3b, X, nullptr);
}

// Round 10
// 209.285 us; speedup vs baseline: 1.0514x; 1.0514x over previous
//
#include <hip/hip_runtime.h>
#include <math.h>

#define EPS 1e-5f

typedef unsigned short ushort_t;
typedef __attribute__((ext_vector_type(8))) __bf16 bf16x8;
typedef __attribute__((ext_vector_type(4))) __bf16 bf16x4;
typedef __attribute__((ext_vector_type(4))) float f32x4;

#define MFMA16(a, b, c) __builtin_amdgcn_mfma_f32_16x16x32_bf16(a, b, c, 0, 0, 0)

// 0.125 (attn scale) * log2(e): folded into Q at the QKV epilogue so the
// attention softmax runs directly in base-2 (v_exp_f32 = 2^x).
#define QSCALE2 0.18033688011112042f

__device__ __forceinline__ unsigned short f2bf(float f) {
  unsigned u = __float_as_uint(f);
  u += 0x7fffu + ((u >> 16) & 1u);
  return (unsigned short)(u >> 16);
}

__device__ __forceinline__ void gload16(const void* g, void* l) {
  __builtin_amdgcn_global_load_lds(
      (__attribute__((address_space(1))) void*)(g),
      (__attribute__((address_space(3))) void*)(l), 16, 0, 0);
}

// ---------------- fused cast f32 -> bf16 for all weights + q ----------------
__global__ __launch_bounds__(256) void cast_all_k(
    const float* __restrict__ wq, const float* __restrict__ wk,
    const float* __restrict__ wv, const float* __restrict__ wo,
    const float* __restrict__ w1, const float* __restrict__ w2,
    const float* __restrict__ q, ushort_t* __restrict__ wqkv,
    ushort_t* __restrict__ wob, ushort_t* __restrict__ w1b,
    ushort_t* __restrict__ w2b, ushort_t* __restrict__ qbf) {
  const int b = blockIdx.x;
  const float* src;
  ushort_t* dst;
  int idx;
  if (b < 2048) {
    const int s = b >> 9;
    src = (s == 0) ? wq : (s == 1) ? wk : (s == 2) ? wv : wo;
    dst = (s == 3) ? wob : wqkv + s * 1048576;
    idx = (b & 511) * 2048 + threadIdx.x * 8;
  } else if (b < 4096) {
    src = w1; dst = w1b; idx = (b - 2048) * 2048 + threadIdx.x * 8;
  } else if (b < 6144) {
    src = w2; dst = w2b; idx = (b - 4096) * 2048 + threadIdx.x * 8;
  } else {
    src = q; dst = qbf; idx = (b - 6144) * 2048 + threadIdx.x * 8;
  }
  float4 a = *(const float4*)(src + idx);
  float4 c = *(const float4*)(src + idx + 4);
  uint4 u;
  u.x = (unsigned)f2bf(a.x) | ((unsigned)f2bf(a.y) << 16);
  u.y = (unsigned)f2bf(a.z) | ((unsigned)f2bf(a.w) << 16);
  u.z = (unsigned)f2bf(c.x) | ((unsigned)f2bf(c.y) << 16);
  u.w = (unsigned)f2bf(c.z) | ((unsigned)f2bf(c.w) << 16);
  *(uint4*)(dst + idx) = u;
}

// ---------------- BN eval params (both BNs in one launch) ----------------
__global__ __launch_bounds__(256) void bnparam_k(
    const float* __restrict__ g1, const float* __restrict__ b1,
    const float* __restrict__ m1, const float* __restrict__ v1,
    const float* __restrict__ g2, const float* __restrict__ b2,
    const float* __restrict__ m2, const float* __restrict__ v2,
    float* __restrict__ sc1, float* __restrict__ sh1,
    float* __restrict__ sc2, float* __restrict__ sh2) {
  int i = blockIdx.x * 256 + threadIdx.x;
  if (i < 4096) {
    float s = g1[i] * rsqrtf(v1[i] + EPS);
    sc1[i] = s;
    sh1[i] = b1[i] - m1[i] * s;
  } else if (i < 5120) {
    int j = i - 4096;
    float s = g2[j] * rsqrtf(v2[j] + EPS);
    sc2[j] = s;
    sh2[j] = b2[j] - m2[j] * s;
  }
}

// ---------------- 2-phase GEMM  C[m,n] = sum_k A[m,k]*W[n,k] ----------------
template <int KDIM, int EPI, int TM, int TN, int WM, int WN, int NTHR, int GX, int GY>
__global__ __launch_bounds__(NTHR, 2) void gemm_bt(const ushort_t* __restrict__ A,
                                                   const ushort_t* __restrict__ W,
                                                   const float* __restrict__ p0,
                                                   const float* __restrict__ p1,
                                                   const float* __restrict__ p2,
                                                   float* __restrict__ outF,
                                                   ushort_t* __restrict__ outB) {
  constexpr int BM = 16 * TM * WM, BN = 16 * TN * WN;
  constexpr int LDS_STAGE = 2 * (BM + BN) * 128;  // bytes, 2 bufs
  constexpr int LDS_TR = (EPI == 0) ? 128 * 136 * 2 : 0;
  __shared__ alignas(16) char pool[(LDS_STAGE > LDS_TR) ? LDS_STAGE : LDS_TR];
  constexpr int LA = BM * 8 / NTHR;  // 16B loads per thread for A tile
  constexpr int LB = BN * 8 / NTHR;

  constexpr int NWG = GX * GY;
  const int id = blockIdx.x;
  const int pos = (id & 7) * (NWG / 8) + (id >> 3);
  const int grp = pos / (8 * GX);
  const int rem = pos % (8 * GX);
  const int by = grp * 8 + (rem & 7);
  const int bx = rem >> 3;
  const int bm = by * BM, bn = bx * BN;

  const int tid = threadIdx.x;
  const int lane = tid & 63;
  const int wid = tid >> 6;
  const int wr = wid / WN, wc = wid % WN;
  const int fr = lane & 15;
  const int kg = lane >> 4;

  const char* Ag0 = (const char*)(A + (size_t)bm * KDIM);
  const char* Bg0 = (const char*)(W + (size_t)bn * KDIM);

#define STAGE(bufi, t_)                                                        \
  do {                                                                         \
    const char* Ag = Ag0 + (size_t)(t_)*128;                                   \
    const char* Bg = Bg0 + (size_t)(t_)*128;                                   \
    char* Ab = pool + (bufi) * (BM * 128);                                     \
    char* Bb = pool + 2 * BM * 128 + (bufi) * (BN * 128);                      \
    _Pragma("unroll") for (int li = 0; li < LA; ++li) {                        \
      const int f = li * NTHR + tid;                                           \
      const int row = f >> 3;                                                  \
      const int gl = (f & 7) ^ (row & 7);                                      \
      gload16(Ag + (size_t)row * (KDIM * 2) + gl * 16,                         \
              Ab + (li * NTHR + wid * 64) * 16);                               \
    }                                                                          \
    _Pragma("unroll") for (int li = 0; li < LB; ++li) {                        \
      const int f = li * NTHR + tid;                                           \
      const int row = f >> 3;                                                  \
      const int gl = (f & 7) ^ (row & 7);                                      \
      gload16(Bg + (size_t)row * (KDIM * 2) + gl * 16,                         \
              Bb + (li * NTHR + wid * 64) * 16);                               \
    }                                                                          \
  } while (0)

  f32x4 acc[TM][TN];
#pragma unroll
  for (int i = 0; i < TM; ++i)
#pragma unroll
    for (int j = 0; j < TN; ++j)
#pragma unroll
      for (int r = 0; r < 4; ++r) acc[i][j][r] = 0.f;

  STAGE(0, 0);
  asm volatile("s_waitcnt vmcnt(0)" ::: "memory");
  __builtin_amdgcn_s_barrier();

  constexpr int NT = KDIM / 64;
  for (int t = 0; t < NT; ++t) {
    const int b = t & 1;
    if (t + 1 < NT) STAGE(b ^ 1, t + 1);  // prefetch flies under compute
    const char* Ac = pool + b * (BM * 128);
    const char* Bc = pool + 2 * BM * 128 + b * (BN * 128);
#pragma unroll
    for (int s = 0; s < 2; ++s) {
      bf16x8 bfv[TN];
#pragma unroll
      for (int nf = 0; nf < TN; ++nf) {
        const int row = wc * (16 * TN) + nf * 16 + fr;
        bfv[nf] = *(const bf16x8*)(Bc + row * 128 + (((s * 4 + kg) ^ (row & 7)) * 16));
      }
#pragma unroll
      for (int mf = 0; mf < TM; ++mf) {
        const int row = wr * (16 * TM) + mf * 16 + fr;
        bf16x8 af = *(const bf16x8*)(Ac + row * 128 + (((s * 4 + kg) ^ (row & 7)) * 16));
#pragma unroll
        for (int nf = 0; nf < TN; ++nf) acc[mf][nf] = MFMA16(af, bfv[nf], acc[mf][nf]);
      }
    }
    asm volatile("s_waitcnt vmcnt(0)" ::: "memory");
    __builtin_amdgcn_s_barrier();
  }
#undef STAGE

  if constexpr (EPI == 0) {
    if (bn < 2048) {
#pragma unroll
      for (int mf = 0; mf < TM; ++mf) {
#pragma unroll
        for (int nf = 0; nf < TN; ++nf) {
#pragma unroll
          for (int r = 0; r < 4; ++r) {
            const int m = bm + wr * (16 * TM) + mf * 16 + kg * 4 + r;
            const int n = bn + wc * (16 * TN) + nf * 16 + fr;
            const int sel = n >> 10;
            const int nl = n & 1023;
            float v = acc[mf][nf][r] + ((sel == 0) ? p0[nl] : p1[nl]);
            if (sel == 0) v *= QSCALE2;
            const int b_ = m >> 10, tok = m & 1023;
            const int h_ = nl >> 6, d_ = nl & 63;
            outB[(size_t)sel * 4194304 + (((size_t)(b_ * 16 + h_) * 1024 + tok) * 64 + d_)] =
                f2bf(v);
          }
        }
      }
    } else {
      __syncthreads();
      ushort_t* T = (ushort_t*)pool;  // [128 n][136 m-pad]
#pragma unroll
      for (int mf = 0; mf < TM; ++mf) {
#pragma unroll
        for (int nf = 0; nf < TN; ++nf) {
          const int ml = wr * (16 * TM) + mf * 16 + kg * 4;
          const int nl = wc * (16 * TN) + nf * 16 + fr;
          const float bias = p2[(bn & 1023) + nl];
          bf16x4 pw;
#pragma unroll
          for (int r = 0; r < 4; ++r) pw[r] = (__bf16)(acc[mf][nf][r] + bias);
          *(bf16x4*)(T + nl * 136 + ml) = pw;
        }
      }
      __syncthreads();
      const int b_ = bm >> 10;
      const int tokb = bm & 1023;
#pragma unroll
      for (int it = 0; it < 8; ++it) {
        const int g = it * 256 + tid;
        const int nl = g >> 4;
        const int m0 = (g & 15) * 8;
        bf16x8 v = *(const bf16x8*)(T + nl * 136 + m0);
        const int nloc = (bn - 2048) + nl;
        const int h_ = nloc >> 6, d_ = nloc & 63;
        *(bf16x8*)(outB + 8388608 + (((size_t)(b_ * 16 + h_) * 64 + d_) << 10) + tokb + m0) = v;
      }
    }
  } else {
#pragma unroll
    for (int mf = 0; mf < TM; ++mf) {
#pragma unroll
      for (int nf = 0; nf < TN; ++nf) {
#pragma unroll
        for (int r = 0; r < 4; ++r) {
          const int m = bm + wr * (16 * TM) + mf * 16 + kg * 4 + r;
          const int n = bn + wc * (16 * TN) + nf * 16 + fr;
          float v = acc[mf][nf][r];
          if constexpr (EPI == 1) {
            v += p0[n] + p1[(size_t)m * 1024 + n];
            outF[(size_t)m * 1024 + n] = v;
          } else if constexpr (EPI == 2) {
            // tanh-form GELU (|err| vs exact erf <= ~3e-3)
            float tt = v * p0[n] + p1[n];
            float u = tt * (0.7978845608f + 0.0356774081f * tt * tt);
            float e = exp2f(u * 2.8853900818f);  // e^{2u}
            float ge = tt * (1.f - 1.f / (e + 1.f));
            outB[(size_t)m * 4096 + n] = f2bf(ge);
          } else {
            outF[(size_t)m * 1024 + n] = v * p0[n] + p1[n];
          }
        }
      }
    }
  }
}

// ---------------- 3-stage counted-vmcnt GEMM (MLP2: BN -> f32) ----------------
template <int KDIM, int TM, int TN, int GX, int GY>
__global__ __launch_bounds__(256, 2) void gemm3s(const ushort_t* __restrict__ A,
                                                 const ushort_t* __restrict__ W,
                                                 const float* __restrict__ sc,
                                                 const float* __restrict__ sh,
                                                 float* __restrict__ outF) {
  constexpr int BM = 32 * TM, BN = 32 * TN;
  __shared__ alignas(16) char pool[3 * (BM + BN) * 128];
  constexpr int LA = BM * 8 / 256;
  constexpr int LB = BN * 8 / 256;

  constexpr int NWG = GX * GY;
  const int id = blockIdx.x;
  const int pos = (id & 7) * (NWG / 8) + (id >> 3);
  const int grp = pos / (8 * GX);
  const int rem = pos % (8 * GX);
  const int by = grp * 8 + (rem & 7);
  const int bx = rem >> 3;
  const int bm = by * BM, bn = bx * BN;

  const int tid = threadIdx.x;
  const int lane = tid & 63;
  const int wid = tid >> 6;
  const int wr = wid >> 1, wc = wid & 1;
  const int fr = lane & 15;
  const int kg = lane >> 4;

  const char* Ag0 = (const char*)(A + (size_t)bm * KDIM);
  const char* Bg0 = (const char*)(W + (size_t)bn * KDIM);

#define STAGE3(bufi, t_)                                                       \
  do {                                                                         \
    const char* Ag = Ag0 + (size_t)(t_)*128;                                   \
    const char* Bg = Bg0 + (size_t)(t_)*128;                                   \
    char* Ab = pool + (bufi) * (BM * 128);                                     \
    char* Bb = pool + 3 * BM * 128 + (bufi) * (BN * 128);                      \
    _Pragma("unroll") for (int li = 0; li < LA; ++li) {                        \
      const int f = li * 256 + tid;                                            \
      const int row = f >> 3;                                                  \
      const int gl = (f & 7) ^ (row & 7);                                      \
      gload16(Ag + (size_t)row * (KDIM * 2) + gl * 16,                         \
              Ab + (li * 256 + wid * 64) * 16);                                \
    }                                                                          \
    _Pragma("unroll") for (int li = 0; li < LB; ++li) {                        \
      const int f = li * 256 + tid;                                            \
      const int row = f >> 3;                                                  \
      const int gl = (f & 7) ^ (row & 7);                                      \
      gload16(Bg + (size_t)row * (KDIM * 2) + gl * 16,                         \
              Bb + (li * 256 + wid * 64) * 16);                                \
    }                                                                          \
  } while (0)

  f32x4 acc[TM][TN];
#pragma unroll
  for (int i = 0; i < TM; ++i)
#pragma unroll
    for (int j = 0; j < TN; ++j)
#pragma unroll
      for (int r = 0; r < 4; ++r) acc[i][j][r] = 0.f;

  STAGE3(0, 0);
  STAGE3(1, 1);
  asm volatile("s_waitcnt vmcnt(6)" ::: "memory");
  __builtin_amdgcn_s_barrier();

  constexpr int NT = KDIM / 64;
  int cb = 0;
  for (int t = 0; t < NT; ++t) {
    if (t + 2 < NT) {
      const int nb = (cb + 2 >= 3) ? cb - 1 : cb + 2;
      STAGE3(nb, t + 2);
    }
    const char* Ac = pool + cb * (BM * 128);
    const char* Bc = pool + 3 * BM * 128 + cb * (BN * 128);
#pragma unroll
    for (int s = 0; s < 2; ++s) {
      bf16x8 bfv[TN];
#pragma unroll
      for (int nf = 0; nf < TN; ++nf) {
        const int row = wc * (16 * TN) + nf * 16 + fr;
        bfv[nf] = *(const bf16x8*)(Bc + row * 128 + (((s * 4 + kg) ^ (row & 7)) * 16));
      }
#pragma unroll
      for (int mf = 0; mf < TM; ++mf) {
        const int row = wr * (16 * TM) + mf * 16 + fr;
        bf16x8 af = *(const bf16x8*)(Ac + row * 128 + (((s * 4 + kg) ^ (row & 7)) * 16));
#pragma unroll
        for (int nf = 0; nf < TN; ++nf) acc[mf][nf] = MFMA16(af, bfv[nf], acc[mf][nf]);
      }
    }
    if (t + 2 < NT)
      asm volatile("s_waitcnt vmcnt(6)" ::: "memory");
    else
      asm volatile("s_waitcnt vmcnt(0)" ::: "memory");
    asm volatile("s_waitcnt lgkmcnt(0)" ::: "memory");
    __builtin_amdgcn_s_barrier();
    cb = (cb + 1 >= 3) ? 0 : cb + 1;
  }
#undef STAGE3

#pragma unroll
  for (int mf = 0; mf < TM; ++mf) {
#pragma unroll
    for (int nf = 0; nf < TN; ++nf) {
      const int n = bn + wc * (16 * TN) + nf * 16 + fr;
      const float scn = sc[n], shn = sh[n];
#pragma unroll
      for (int r = 0; r < 4; ++r) {
        const int m = bm + wr * (16 * TM) + mf * 16 + kg * 4 + r;
        outF[(size_t)m * 1024 + n] = acc[mf][nf][r] * scn + shn;
      }
    }
  }
}

// ---------------- flash attention (swapped QK^T, LDS-staged K/V, dbuf) -------
// + defer-max (T13): skip O-rescale when per-tile max growth <= 8*log2e.
__global__ __launch_bounds__(512) void attn_k(const ushort_t* __restrict__ qp,
                                              const ushort_t* __restrict__ kp,
                                              const ushort_t* __restrict__ vt,
                                              ushort_t* __restrict__ aout) {
  __shared__ ushort_t Kt[2][4096];
  __shared__ ushort_t Vt[2][4096];
  __shared__ ushort_t P[8][16][72];
  const int tid = threadIdx.x;
  const int lane = tid & 63;
  const int wid = tid >> 6;
  const int fr = lane & 15;
  const int kg = lane >> 4;
  const int id = blockIdx.x;
  const int slot = id >> 3;
  const int bh = ((id & 7) << 3) | (slot >> 3);  // 8 heads per XCD chunk
  const int qc = slot & 7;
  const int b_ = bh >> 4, h_ = bh & 15;

  const size_t base = (size_t)bh << 10;
  const int qrow = qc * 128 + wid * 16 + fr;
  bf16x8 qf0 = *(const bf16x8*)(qp + ((base + qrow) << 6) + kg * 8);
  bf16x8 qf1 = *(const bf16x8*)(qp + ((base + qrow) << 6) + 32 + kg * 8);

  const int srow = tid >> 3;
  const int sg16 = ((tid & 7) ^ (srow & 7)) * 16;
  const char* kTileB = (const char*)kp + ((size_t)bh << 17);
  const char* vTileB = (const char*)vt + ((size_t)bh << 17);
  const size_t koff = (size_t)srow * 128 + sg16;   // + kt*8192
  const size_t voff = (size_t)srow * 2048 + sg16;  // + kt*128

#define STAGE(bufi, kt_)                                                      \
  do {                                                                        \
    gload16(kTileB + (size_t)(kt_)*8192 + koff, (char*)Kt[bufi] + wid * 1024); \
    gload16(vTileB + (size_t)(kt_)*128 + voff, (char*)Vt[bufi] + wid * 1024);  \
  } while (0)

  f32x4 oacc[4];
#pragma unroll
  for (int d = 0; d < 4; ++d)
#pragma unroll
    for (int r = 0; r < 4; ++r) oacc[d][r] = 0.f;
  float mrun = -3.0e38f, lrun = 0.f;

  STAGE(0, 0);
  __syncthreads();

  for (int kt = 0; kt < 16; ++kt) {
    const int c = kt & 1;
    if (kt < 15) STAGE(c ^ 1, kt + 1);
    const char* Kc = (const char*)Kt[c];
    const char* Vc = (const char*)Vt[c];

    f32x4 sacc[4];
#pragma unroll
    for (int nf = 0; nf < 4; ++nf)
#pragma unroll
      for (int r = 0; r < 4; ++r) sacc[nf][r] = 0.f;
    __builtin_amdgcn_s_setprio(1);
#pragma unroll
    for (int nf = 0; nf < 4; ++nf) {
      const int r_ = nf * 16 + fr;
      const char* kr = Kc + r_ * 128;
      bf16x8 kf0 = *(const bf16x8*)(kr + ((kg ^ (r_ & 7)) * 16));
      bf16x8 kf1 = *(const bf16x8*)(kr + (((kg + 4) ^ (r_ & 7)) * 16));
      sacc[nf] = MFMA16(kf0, qf0, sacc[nf]);
      sacc[nf] = MFMA16(kf1, qf1, sacc[nf]);
    }
    __builtin_amdgcn_s_setprio(0);
    float mx = sacc[0][0];
#pragma unroll
    for (int nf = 0; nf < 4; ++nf)
#pragma unroll
      for (int r = 0; r < 4; ++r) mx = fmaxf(mx, sacc[nf][r]);
    mx = fmaxf(mx, __shfl_xor(mx, 16));
    mx = fmaxf(mx, __shfl_xor(mx, 32));
    // defer-max: if the tile max grew by <= 8*log2e (base-2 logits), keep the
    // old running max -- P bounded by 2^11.54, f32/bf16 headroom is ample.
    const bool skip = __all((mx - mrun) <= 11.5416f);
    const float mn = skip ? mrun : fmaxf(mrun, mx);
    float rs = 0.f;
#pragma unroll
    for (int nf = 0; nf < 4; ++nf) {
      bf16x4 pw;
#pragma unroll
      for (int r = 0; r < 4; ++r) {
        float ev = exp2f(sacc[nf][r] - mn);
        rs += ev;
        pw[r] = (__bf16)ev;
      }
      *(bf16x4*)(&P[wid][fr][nf * 16 + kg * 4]) = pw;
    }
    rs += __shfl_xor(rs, 16);
    rs += __shfl_xor(rs, 32);
    if (skip) {
      lrun += rs;
    } else {
      const float c_ = exp2f(mrun - mn);
      lrun = lrun * c_ + rs;
      mrun = mn;
      float cb[4];
#pragma unroll
      for (int r = 0; r < 4; ++r) cb[r] = __shfl(c_, kg * 4 + r);
#pragma unroll
      for (int d = 0; d < 4; ++d)
#pragma unroll
        for (int r = 0; r < 4; ++r) oacc[d][r] *= cb[r];
    }
    bf16x8 pa0 = *(const bf16x8*)(&P[wid][fr][kg * 8]);
    bf16x8 pa1 = *(const bf16x8*)(&P[wid][fr][32 + kg * 8]);
    __builtin_amdgcn_s_setprio(1);
#pragma unroll
    for (int df = 0; df < 4; ++df) {
      const int r_ = df * 16 + fr;
      const char* vr_ = Vc + r_ * 128;
      bf16x8 vf0 = *(const bf16x8*)(vr_ + ((kg ^ (r_ & 7)) * 16));
      bf16x8 vf1 = *(const bf16x8*)(vr_ + (((kg + 4) ^ (r_ & 7)) * 16));
      oacc[df] = MFMA16(pa0, vf0, oacc[df]);
      oacc[df] = MFMA16(pa1, vf1, oacc[df]);
    }
    __builtin_amdgcn_s_setprio(0);
    __syncthreads();
  }
#undef STAGE

  float linv[4];
#pragma unroll
  for (int r = 0; r < 4; ++r) linv[r] = 1.f / __shfl(lrun, kg * 4 + r);
#pragma unroll
  for (int df = 0; df < 4; ++df) {
#pragma unroll
    for (int r = 0; r < 4; ++r) {
      const int tok = qc * 128 + wid * 16 + kg * 4 + r;
      const int d_ = df * 16 + fr;
      aout[((size_t)(b_ * 1024 + tok) * 16 + h_) * 64 + d_] = f2bf(oacc[df][r] * linv[r]);
    }
  }
}

// ---------------- LayerNorm over rows of 1024 ----------------
template <int MODE>
__global__ __launch_bounds__(256) void ln_k(const float* __restrict__ in1,
                                            const float* __restrict__ in2,
                                            const float* __restrict__ g,
                                            const float* __restrict__ bt,
                                            float* __restrict__ outF,
                                            ushort_t* __restrict__ outB) {
  const int row = blockIdx.x;
  const int tid = threadIdx.x;
  const size_t off = (size_t)row * 1024 + tid * 4;
  float4 v = *(const float4*)(in1 + off);
  if (MODE == 1) {
    float4 u = *(const float4*)(in2 + off);
    v.x += u.x; v.y += u.y; v.z += u.z; v.w += u.w;
  }
  float s = v.x + v.y + v.z + v.w;
  float q = v.x * v.x + v.y * v.y + v.z * v.z + v.w * v.w;
#pragma unroll
  for (int o = 32; o > 0; o >>= 1) {
    s += __shfl_down(s, o);
    q += __shfl_down(q, o);
  }
  __shared__ float rs[4], rq[4], stat[2];
  const int wid = tid >> 6, lane = tid & 63;
  if (lane == 0) { rs[wid] = s; rq[wid] = q; }
  __syncthreads();
  if (tid == 0) {
    float S = rs[0] + rs[1] + rs[2] + rs[3];
    float Q = rq[0] + rq[1] + rq[2] + rq[3];
    float mean = S * (1.f / 1024.f);
    float var = Q * (1.f / 1024.f) - mean * mean;
    stat[0] = mean;
    stat[1] = rsqrtf(var + EPS);
  }
  __syncthreads();
  const float mean = stat[0], rstd = stat[1];
  const int c = tid * 4;
  float4 o4;
  o4.x = (v.x - mean) * rstd * g[c] + bt[c];
  o4.y = (v.y - mean) * rstd * g[c + 1] + bt[c + 1];
  o4.z = (v.z - mean) * rstd * g[c + 2] + bt[c + 2];
  o4.w = (v.w - mean) * rstd * g[c + 3] + bt[c + 3];
  *(float4*)(outF + off) = o4;
  if (MODE == 0) {
    ushort4 ub;
    ub.x = f2bf(o4.x); ub.y = f2bf(o4.y); ub.z = f2bf(o4.z); ub.w = f2bf(o4.w);
    *(ushort4*)(outB + off) = ub;
  }
}

extern "C" void kernel_launch(void* const* d_in, const int* in_sizes, int n_in,
                              void* d_out, int out_size, void* d_ws, size_t ws_size,
                              hipStream_t stream) {
  const float* q    = (const float*)d_in[0];
  const float* wq   = (const float*)d_in[1];
  const float* bq   = (const float*)d_in[2];
  const float* wk   = (const float*)d_in[3];
  const float* bk   = (const float*)d_in[4];
  const float* wv   = (const float*)d_in[5];
  const float* bv   = (const float*)d_in[6];
  const float* wo   = (const float*)d_in[7];
  const float* bo   = (const float*)d_in[8];
  const float* w1   = (const float*)d_in[9];
  const float* bn1g = (const float*)d_in[10];
  const float* bn1b = (const float*)d_in[11];
  const float* bn1m = (const float*)d_in[12];
  const float* bn1v = (const float*)d_in[13];
  const float* w2   = (const float*)d_in[14];
  const float* bn2g = (const float*)d_in[15];
  const float* bn2b = (const float*)d_in[16];
  const float* bn2m = (const float*)d_in[17];
  const float* bn2v = (const float*)d_in[18];
  const float* ln1g = (const float*)d_in[19];
  const float* ln1b = (const float*)d_in[20];
  const float* ln3g = (const float*)d_in[21];
  const float* ln3b = (const float*)d_in[22];

  char* ws = (char*)d_ws;
  const size_t MB = 1u << 20;
  ushort_t* wqkv = (ushort_t*)(ws);            // 6 MB  [3072,1024]
  ushort_t* w1b  = (ushort_t*)(ws + 6 * MB);   // 8 MB  [4096,1024]
  ushort_t* w2b  = (ushort_t*)(ws + 14 * MB);  // 8 MB  [1024,4096]
  ushort_t* wob  = (ushort_t*)(ws + 22 * MB);  // 2 MB  [1024,1024]
  float* sc1 = (float*)(ws + 24 * MB);
  float* sh1 = sc1 + 4096;
  float* sc2 = sh1 + 4096;
  float* sh2 = sc2 + 1024;
  ushort_t* qbf  = (ushort_t*)(ws + 25 * MB);  // 8 MB
  ushort_t* qp   = (ushort_t*)(ws + 33 * MB);  // 8+8+8 MB (qp,kp,vt contiguous)
  ushort_t* aout = (ushort_t*)(ws + 57 * MB);  // 8 MB
  ushort_t* xbf  = (ushort_t*)(ws + 65 * MB);  // 8 MB
  float*    h2   = (float*)(ws + 73 * MB);     // 16 MB
  ushort_t* h1   = (ushort_t*)(ws + 33 * MB);  // 32 MB (reuses qp/kp/vt/aout)
  float* X = (float*)d_out;                    // x lives in d_out (16 MB)

  const int NM = 1024 * 1024;
  cast_all_k<<<8192, 256, 0, stream>>>(wq, wk, wv, wo, w1, w2, q, wqkv, wob, w1b, w2b, qbf);
  bnparam_k<<<20, 256, 0, stream>>>(bn1g, bn1b, bn1m, bn1v, bn2g, bn2b, bn2m, bn2v,
                                    sc1, sh1, sc2, sh2);

  // fused QKV projection: [4096,1024] x [3072,1024]^T, 128x128 dbuf
  gemm_bt<1024, 0, 4, 4, 2, 2, 256, 24, 32><<<768, 256, 0, stream>>>(
      qbf, wqkv, bq, bk, bv, nullptr, qp);
  // attention (512 blocks x 512 threads, LDS-staged K/V double-buffered)
  attn_k<<<512, 512, 0, stream>>>(qp, qp + 4 * NM, qp + 8 * NM, aout);
  // O projection + bias + residual -> X (f32, in d_out), 128x64 dbuf
  gemm_bt<1024, 1, 4, 2, 2, 2, 256, 16, 32><<<512, 256, 0, stream>>>(
      aout, wob, bo, q, nullptr, X, nullptr);
  // LN1 -> X (in place) + xbf
  ln_k<0><<<4096, 256, 0, stream>>>(X, nullptr, ln1g, ln1b, X, xbf);
  // MLP1: [4096,1024] x [4096,1024]^T -> BN+GELU(tanh) -> h1 bf16, 256x256 8-wave dbuf
  gemm_bt<1024, 2, 8, 4, 2, 4, 512, 16, 16><<<256, 512, 0, stream>>>(
      xbf, w1b, sc1, sh1, nullptr, nullptr, h1);
  // MLP2: [4096,4096] x [1024,4096]^T -> BN -> h2 f32, 128x64 3-stage counted-vmcnt
  gemm3s<4096, 4, 2, 16, 32><<<512, 256, 0, stream>>>(h1, w2b, sc2, sh2, h2);
  // LN3(X + h2) -> d_out
  ln_k<1><<<4096, 256, 0, stream>>>(X, h2, ln3g, ln3b, X, nullptr);
}